// Round 17
// baseline (63.286 us; speedup 1.0000x reference)
//
#include <hip/hip_runtime.h>
#include <math.h>

#define LAM 0.01f

typedef __bf16 bf16x8 __attribute__((ext_vector_type(8)));
typedef float f32x4 __attribute__((ext_vector_type(4)));
typedef short short8v __attribute__((ext_vector_type(8)));

#define BF(v) __builtin_bit_cast(bf16x8, (v))
#define MFMA __builtin_amdgcn_mfma_f32_16x16x32_bf16
#define LDS_FENCE() do { asm volatile("s_waitcnt lgkmcnt(0)" ::: "memory"); \
                         __builtin_amdgcn_sched_barrier(0); } while (0)

__device__ __forceinline__ unsigned short f2bf(float f) {
    __bf16 h = (__bf16)f;
    return __builtin_bit_cast(unsigned short, h);
}
__device__ __forceinline__ float bf2f(unsigned short u) {
    unsigned int v = ((unsigned int)u) << 16;
    return __builtin_bit_cast(float, v);
}
// seed (c,s) = sc * (cos, sin)(2*pi*(m mod 512)/512)
__device__ __forceinline__ void seed_ang(int m, float sc, float* c, float* s) {
    float sv, cv;
    sincosf(6.28318530717958647692f * (float)(m & 511) * (1.0f / 512.0f), &sv, &cv);
    *c = cv * sc; *s = sv * sc;
}
// unit rotation: (c,s) <- (c*cd - s*sd, c*sd + s*cd); preserves seed scale
#define ROT(c, s, cd, sd) do { float nc_ = fmaf((c), (cd), -(s) * (sd)); \
                               float ns_ = fmaf((c), (sd),  (s) * (cd)); \
                               (c) = nc_; (s) = ns_; } while (0)

// 176 wave-tasks/(b,n), tau = (block_w<<2)|wv. sh = 9-log2(P).
// tau 0..3 are "mega" P=512 tasks (heaviest -> dispatched first).
struct Task { int sh, c16, t_lo, t_hi, jump_s; };
__device__ __forceinline__ Task task_params(int tau) {
    Task tk;
    if (tau < 4)        { tk.sh = 0; tk.c16 = tau * 8; tk.t_lo = 255; tk.t_hi = 255; tk.jump_s = 256; }   // P=512 mega
    else if (tau < 132) { int u = tau - 4;   int seg = u >> 4; tk.sh = 1; tk.c16 = u & 15;
                          tk.t_lo = 127 + 16 * seg; tk.t_hi = tk.t_lo + 15; tk.jump_s = tk.t_lo + 1; }    // P=256
    else if (tau < 164) { int u = tau - 132; int seg = u >> 3; tk.sh = 2; tk.c16 = u & 7;
                          tk.t_lo = 63 + 16 * seg; tk.t_hi = tk.t_lo + 15; tk.jump_s = tk.t_lo + 1; }     // P=128
    else if (tau < 172) { int u = tau - 164; int seg = u >> 2; tk.sh = 3; tk.c16 = u & 3;
                          tk.t_lo = 31 + 16 * seg; tk.t_hi = tk.t_lo + 15; tk.jump_s = tk.t_lo + 1; }     // P=64
    else if (tau < 174) { tk.sh = 4; tk.c16 = tau - 172; tk.t_lo = 15; tk.t_hi = 30; tk.jump_s = 0; }     // P=32
    else if (tau == 174){ tk.sh = 5; tk.c16 = 0; tk.t_lo = 7; tk.t_hi = 14; tk.jump_s = 0; }              // P=16
    else                { tk.sh = 6; tk.c16 = 0; tk.t_lo = 0; tk.t_hi = 6;  tk.jump_s = 0; }              // P=8
    return tk;
}

// MFMA layouts (m89-verified). Layer1 transposed; layer-1 output channels
// permuted so C regs ARE the layer-2 A-fragment (see r10 comments).
// r17: steady-state twiddles via in-register rotation recurrence (seeded by
// sincos once per task, 1/sqrt(P) folded into the epilogue seeds) — removes
// ~10 LDS gathers + index bookkeeping per step (r16: issue-bound at ~70%,
// 3.6M bank-conflict cycles from tw gathers). Tables remain for the jump.
__global__ __launch_bounds__(256, 3)
void afno_mfma(const float* __restrict__ x,
               const float* __restrict__ w1,
               const float* __restrict__ b1,
               const float* __restrict__ w2,
               const float* __restrict__ b2,
               float* __restrict__ out) {
    __shared__ unsigned short xs[8192];   // raw bf16 x, [rows<=256][32]  16 KB
    __shared__ float twc[544];            // cos(2*pi*m/512), idx m+(m>>4) (jump only)
    __shared__ float tws[544];            // sin (jump only)
    __shared__ float jslab[4 * 544];      // per-wave f32 [16][33] jump slab

    int bid = blockIdx.x;
    int w  = bid >> 5;                    // 0..43
    int bn = bid & 31;
    int b = bn >> 3, n = bn & 7;

    int tid = threadIdx.x;
    int wv = tid >> 6;
    int lane = tid & 63;
    int lg = lane >> 4;
    int l15 = lane & 15;
    int krow = lg * 8;

    // ---- stage x rows (raw bf16, padded to a 32-row multiple) + twiddles ----
    int rows = 0;
    #pragma unroll
    for (int q = 0; q < 4; ++q) {
        Task t2 = task_params((w << 2) | q);
        rows = rows > (t2.t_hi + 1) ? rows : (t2.t_hi + 1);
    }
    rows = (rows + 31) & ~31;
    rows = rows > 256 ? 256 : rows;
    for (int idx = tid; idx < rows * 16; idx += 256) {
        int row = idx >> 4, cp = idx & 15;
        float2 v = *(const float2*)(x + (b * 256 + row) * 256 + n * 32 + cp * 2);
        unsigned int pk = (unsigned int)f2bf(v.x) | ((unsigned int)f2bf(v.y) << 16);
        *(unsigned int*)(xs + idx * 2) = pk;
    }
    for (int m = tid; m < 512; m += 256) {
        float sv, cv;
        sincosf(6.28318530717958647692f * (float)m * (1.0f / 512.0f), &sv, &cv);
        twc[m + (m >> 4)] = cv;
        tws[m + (m >> 4)] = sv;
    }

    Task tk = task_params((w << 2) | wv);
    int P = 512 >> tk.sh;
    float invSqrtP = rsqrtf((float)P);

    // ---- weights -> bf16 fragments; W1 carries 1/sqrt(P); W2 rows in chan order ----
    const float* w1r = w1 + n * 1024;
    const float* w1i = w1 + (8 + n) * 1024;
    const float* w2r = w2 + n * 1024;
    const float* w2i = w2 + (8 + n) * 1024;
    short8v W10[2], W11[2], W11n[2], W20[2], W21[2], W21n[2];
    #pragma unroll
    for (int h = 0; h < 2; ++h) {
        int col = h * 16 + l15;
        #pragma unroll
        for (int j = 0; j < 8; ++j) {
            W10[h][j]  = (short)f2bf(w1r[(krow + j) * 32 + col] * invSqrtP);
            W11[h][j]  = (short)f2bf(w1i[(krow + j) * 32 + col] * invSqrtP);
            W11n[h][j] = W11[h][j] ^ (short)0x8000;
            int crow = ((j >> 2) * 16) + (lg * 4) + (j & 3);   // chan permutation
            W20[h][j]  = (short)f2bf(w2r[crow * 32 + col]);
            W21[h][j]  = (short)f2bf(w2i[crow * 32 + col]);
            W21n[h][j] = W21[h][j] ^ (short)0x8000;
        }
    }
    f32x4 b1rv[2], b1iv[2];
    float b2r_[2], b2i_[2];
    #pragma unroll
    for (int h = 0; h < 2; ++h) {
        int base = n * 32 + h * 16 + lg * 4;
        b1rv[h] = f32x4{b1[base], b1[base + 1], b1[base + 2], b1[base + 3]};
        b1iv[h] = f32x4{b1[256 + base], b1[256 + base + 1], b1[256 + base + 2], b1[256 + base + 3]};
        b2r_[h] = b2[n * 32 + h * 16 + l15];
        b2i_[h] = b2[256 + n * 32 + h * 16 + l15];
    }
    __syncthreads();   // only block barrier

    int pA5 = 0;
    int prow5[4];
    float Xre[8] = {0,0,0,0,0,0,0,0}, Xim[8] = {0,0,0,0,0,0,0,0};
    // twiddle recurrence state
    float cA = 1.f, sA = 0.f, cdA = 1.f, sdA = 0.f;
    float cR[4], sR[4], cdR[4], sdR[4];

// Prefix jump via MFMA (tables). jump_s may be a 16-multiple: rows >= jump_s
// in the last K-block get a zeroed twiddle A-fragment.
#define JUMP_X(js_) do { \
        f32x4 jre0 = {0,0,0,0}, jre1 = {0,0,0,0}, jim0 = {0,0,0,0}, jim1 = {0,0,0,0}; \
        int nkk_ = ((js_) + 31) >> 5; \
        int tail_ = (js_) & 31; \
        for (int kk = 0; kk < nkk_; ++kk) { \
            int sb_ = kk * 32; \
            short8v ac_, an2_; \
            bool zb_ = (tail_ != 0) && (kk == nkk_ - 1) && (krow >= tail_); \
            if (zb_) { \
                _Pragma("unroll") \
                for (int j = 0; j < 8; ++j) { ac_[j] = 0; an2_[j] = 0; } \
            } else { \
                int mj_ = (pA5 * (sb_ + krow)) & 511; \
                _Pragma("unroll") \
                for (int j = 0; j < 8; ++j) { \
                    int mi2_ = mj_ + (mj_ >> 4); \
                    ac_[j]  = (short)f2bf(twc[mi2_]); \
                    an2_[j] = (short)f2bf(-tws[mi2_]); \
                    mj_ = (mj_ + pA5) & 511; \
                } \
            } \
            short8v bx0_, bx1_; \
            _Pragma("unroll") \
            for (int j = 0; j < 8; ++j) { \
                int base_ = (sb_ + krow + j) * 32 + l15; \
                bx0_[j] = (short)xs[base_]; \
                bx1_[j] = (short)xs[base_ + 16]; \
            } \
            jre0 = MFMA(BF(ac_),  BF(bx0_), jre0, 0, 0, 0); \
            jim0 = MFMA(BF(an2_), BF(bx0_), jim0, 0, 0, 0); \
            jre1 = MFMA(BF(ac_),  BF(bx1_), jre1, 0, 0, 0); \
            jim1 = MFMA(BF(an2_), BF(bx1_), jim1, 0, 0, 0); \
        } \
        float* jt_ = jslab + wv * 544; \
        _Pragma("unroll") \
        for (int r = 0; r < 4; ++r) { \
            jt_[(lg * 4 + r) * 33 + l15]      = jre0[r]; \
            jt_[(lg * 4 + r) * 33 + 16 + l15] = jre1[r]; \
        } \
        LDS_FENCE(); \
        _Pragma("unroll") \
        for (int j = 0; j < 8; ++j) Xre[j] = jt_[l15 * 33 + krow + j]; \
        LDS_FENCE(); \
        _Pragma("unroll") \
        for (int r = 0; r < 4; ++r) { \
            jt_[(lg * 4 + r) * 33 + l15]      = jim0[r]; \
            jt_[(lg * 4 + r) * 33 + 16 + l15] = jim1[r]; \
        } \
        LDS_FENCE(); \
        _Pragma("unroll") \
        for (int j = 0; j < 8; ++j) Xim[j] = jt_[l15 * 33 + krow + j]; \
        LDS_FENCE(); \
    } while (0)

// DFT update via recurrence twiddle (no LDS except the xs row read)
#define UPDATE_X(sidx) do { \
        short8v xv8 = *(const short8v*)(xs + (sidx) * 32 + krow); \
        _Pragma("unroll") \
        for (int j = 0; j < 8; ++j) { \
            float xf = bf2f((unsigned short)xv8[j]); \
            Xre[j] = fmaf(xf, cA, Xre[j]); \
            Xim[j] = fmaf(xf, -sA, Xim[j]); \
        } \
        ROT(cA, sA, cdA, sdA); } while (0)

#define STEP_CORE(sidx, do_upd, DEST) do { \
        if (do_upd) UPDATE_X(sidx); \
        short8v ar_, ai_; \
        _Pragma("unroll") \
        for (int j = 0; j < 8; ++j) { \
            ar_[j] = (short)f2bf(Xre[j]); \
            ai_[j] = (short)f2bf(Xim[j]); \
        } \
        f32x4 o1r_[2], o1i_[2]; \
        _Pragma("unroll") \
        for (int h = 0; h < 2; ++h) { \
            o1r_[h] = MFMA(BF(W10[h]),  BF(ar_), b1rv[h], 0, 0, 0); \
            o1r_[h] = MFMA(BF(W11n[h]), BF(ai_), o1r_[h], 0, 0, 0); \
            o1i_[h] = MFMA(BF(W10[h]),  BF(ai_), b1iv[h], 0, 0, 0); \
            o1i_[h] = MFMA(BF(W11[h]),  BF(ar_), o1i_[h], 0, 0, 0); \
        } \
        short8v a2r_, a2i_; \
        _Pragma("unroll") \
        for (int j = 0; j < 8; ++j) { \
            a2r_[j] = (short)f2bf(fmaxf(o1r_[j >> 2][j & 3], 0.f)); \
            a2i_[j] = (short)f2bf(fmaxf(o1i_[j >> 2][j & 3], 0.f)); \
        } \
        f32x4 o2r_[2], o2i_[2]; \
        _Pragma("unroll") \
        for (int h = 0; h < 2; ++h) { \
            f32x4 cr = {b2r_[h], b2r_[h], b2r_[h], b2r_[h]}; \
            f32x4 ci = {b2i_[h], b2i_[h], b2i_[h], b2i_[h]}; \
            o2r_[h] = MFMA(BF(a2r_), BF(W20[h]), cr, 0, 0, 0); \
            o2r_[h] = MFMA(BF(a2i_), BF(W21n[h]), o2r_[h], 0, 0, 0); \
            o2i_[h] = MFMA(BF(a2i_), BF(W20[h]), ci, 0, 0, 0); \
            o2i_[h] = MFMA(BF(a2r_), BF(W21[h]), o2i_[h], 0, 0, 0); \
        } \
        float sh0 = 0.f, sh1 = 0.f; \
        _Pragma("unroll") \
        for (int r = 0; r < 4; ++r) { \
            float c_ = cR[r], s_ = sR[r];  /* carries 1/sqrt(P) */ \
            float v0r = o2r_[0][r]; v0r -= __builtin_amdgcn_fmed3f(v0r, -LAM, LAM); \
            float v0i = o2i_[0][r]; v0i -= __builtin_amdgcn_fmed3f(v0i, -LAM, LAM); \
            sh0 = fmaf(v0r, c_, sh0); sh0 = fmaf(-v0i, s_, sh0); \
            float v1r = o2r_[1][r]; v1r -= __builtin_amdgcn_fmed3f(v1r, -LAM, LAM); \
            float v1i = o2i_[1][r]; v1i -= __builtin_amdgcn_fmed3f(v1i, -LAM, LAM); \
            sh1 = fmaf(v1r, c_, sh1); sh1 = fmaf(-v1i, s_, sh1); \
            ROT(cR[r], sR[r], cdR[r], sdR[r]); \
        } \
        sh0 += __shfl_xor(sh0, 16); \
        sh1 += __shfl_xor(sh1, 16); \
        if (P > 8) { sh0 += __shfl_xor(sh0, 32); sh1 += __shfl_xor(sh1, 32); } \
        DEST = (lane & 16) ? sh1 : sh0; \
    } while (0)

    if (tk.jump_s == 256) {
        // ---- mega P=512 wave: 8 chunks, one output row (t=255), one atomic ----
        float acc = 0.f;
        #pragma unroll
        for (int r = 0; r < 4; ++r) { cdR[r] = 1.f; sdR[r] = 0.f; }  // single step: identity delta
        for (int nc = 0; nc < 8; ++nc) {
            int cb_ = (tk.c16 + nc) * 16;
            pA5 = (cb_ + l15) & 511;
            #pragma unroll
            for (int r = 0; r < 4; ++r) {
                prow5[r] = (cb_ + lg * 4 + r) & 511;
                seed_ang(prow5[r] * 255, invSqrtP, &cR[r], &sR[r]);
            }
            JUMP_X(256);
            float v_;
            STEP_CORE(255, false, v_);
            acc += v_;
        }
        if (lane < 32)
            atomicAdd(out + (b * 256 + 255) * 256 + n * 32 + (lane & 31), acc);
        return;
    }

    int cbase = tk.c16 * 16;
    pA5 = ((cbase + l15) << tk.sh) & 511;
    #pragma unroll
    for (int r = 0; r < 4; ++r) {
        prow5[r] = ((cbase + lg * 4 + r) << tk.sh) & 511;
        seed_ang(prow5[r] * tk.t_lo, invSqrtP, &cR[r], &sR[r]);
        seed_ang(prow5[r], 1.f, &cdR[r], &sdR[r]);
    }
    seed_ang(pA5, 1.f, &cdA, &sdA);

    bool jumped = tk.jump_s > 0;
    if (jumped) {
        seed_ang(pA5 * (tk.t_lo + 1), 1.f, &cA, &sA);   // first UPDATE is at s = t_lo+1
        JUMP_X(tk.jump_s);
    } else {
        cA = 1.f; sA = 0.f;                              // s = 0 start
        for (int s = 0; s < tk.t_lo; ++s) UPDATE_X(s);
    }

    int s = tk.t_lo;
    bool skip0 = jumped;
    while (s + 1 <= tk.t_hi) {
        {
            float v_;
            STEP_CORE(s, !skip0, v_);
            if (lane < 32)
                atomicAdd(out + (b * 256 + s) * 256 + n * 32 + (lane & 31), v_);
        }
        {
            float v_;
            STEP_CORE(s + 1, true, v_);
            if (lane < 32)
                atomicAdd(out + (b * 256 + s + 1) * 256 + n * 32 + (lane & 31), v_);
        }
        skip0 = false;
        s += 2;
    }
    if (s <= tk.t_hi) {
        float v_;
        STEP_CORE(s, !skip0, v_);
        if (lane < 32)
            atomicAdd(out + (b * 256 + s) * 256 + n * 32 + (lane & 31), v_);
    }
}

extern "C" void kernel_launch(void* const* d_in, const int* in_sizes, int n_in,
                              void* d_out, int out_size, void* d_ws, size_t ws_size,
                              hipStream_t stream) {
    const float* x  = (const float*)d_in[0];
    const float* w1 = (const float*)d_in[1];
    const float* b1 = (const float*)d_in[2];
    const float* w2 = (const float*)d_in[3];
    const float* b2 = (const float*)d_in[4];
    float* out = (float*)d_out;

    // out = x (the "+ x" residual), then the main kernel atomically accumulates.
    hipMemcpyAsync(out, x, (size_t)(4 * 256 * 256) * sizeof(float),
                   hipMemcpyDeviceToDevice, stream);
    hipLaunchKernelGGL(afno_mfma, dim3(1408), dim3(256), 0, stream,
                       x, w1, b1, w2, b2, out);
}

// Round 18
// 58.199 us; speedup vs baseline: 1.0874x; 1.0874x over previous
//
#include <hip/hip_runtime.h>
#include <math.h>

#define LAM 0.01f

typedef __bf16 bf16x8 __attribute__((ext_vector_type(8)));
typedef float f32x4 __attribute__((ext_vector_type(4)));
typedef short short8v __attribute__((ext_vector_type(8)));
typedef short short4v __attribute__((ext_vector_type(4)));

#define BF(v) __builtin_bit_cast(bf16x8, (v))
#define MFMA __builtin_amdgcn_mfma_f32_16x16x32_bf16
#define XROW 36   // xs row stride in shorts: 72B -> lg-groups 2-way banks (free);
                  // 32 put all 4 lg-groups on one bank (8-way, r16's 3.6M cyc)
#define LDS_FENCE() do { asm volatile("s_waitcnt lgkmcnt(0)" ::: "memory"); \
                         __builtin_amdgcn_sched_barrier(0); } while (0)

__device__ __forceinline__ unsigned short f2bf(float f) {
    __bf16 h = (__bf16)f;
    return __builtin_bit_cast(unsigned short, h);
}
__device__ __forceinline__ float bf2f(unsigned short u) {
    unsigned int v = ((unsigned int)u) << 16;
    return __builtin_bit_cast(float, v);
}

// 188 wave-tasks/(b,n), tau = (block_w<<2)|wv. sh = 9-log2(P); twiddles in
// 512-space. 16-step t-segments. Mega P=512 tasks now cover only 2 chunks each
// (16 tasks) so the longest serial chain ~matches a P=256 task (r16's 8-chunk
// megas were ~2.3x longer and pinned the tail).
struct Task { int sh, c16, t_lo, t_hi, jump_s; };
__device__ __forceinline__ Task task_params(int tau) {
    Task tk;
    if (tau < 16)       { tk.sh = 0; tk.c16 = tau * 2; tk.t_lo = 255; tk.t_hi = 255; tk.jump_s = 256; }   // P=512 mega2
    else if (tau < 144) { int u = tau - 16;  int seg = u >> 4; tk.sh = 1; tk.c16 = u & 15;
                          tk.t_lo = 127 + 16 * seg; tk.t_hi = tk.t_lo + 15; tk.jump_s = tk.t_lo + 1; }    // P=256
    else if (tau < 176) { int u = tau - 144; int seg = u >> 3; tk.sh = 2; tk.c16 = u & 7;
                          tk.t_lo = 63 + 16 * seg; tk.t_hi = tk.t_lo + 15; tk.jump_s = tk.t_lo + 1; }     // P=128
    else if (tau < 184) { int u = tau - 176; int seg = u >> 2; tk.sh = 3; tk.c16 = u & 3;
                          tk.t_lo = 31 + 16 * seg; tk.t_hi = tk.t_lo + 15; tk.jump_s = tk.t_lo + 1; }     // P=64
    else if (tau < 186) { tk.sh = 4; tk.c16 = tau - 184; tk.t_lo = 15; tk.t_hi = 30; tk.jump_s = 0; }     // P=32
    else if (tau == 186){ tk.sh = 5; tk.c16 = 0; tk.t_lo = 7; tk.t_hi = 14; tk.jump_s = 0; }              // P=16
    else                { tk.sh = 6; tk.c16 = 0; tk.t_lo = 0; tk.t_hi = 6;  tk.jump_s = 0; }              // P=8
    return tk;
}

// MFMA layouts (m89-verified): A row=lane&15,k=(lane>>4)*8+j; B k=(lane>>4)*8+j,
// col=lane&15; C/D col=lane&15,row=(lane>>4)*4+reg.
// Layer1 transposed (o1^T = W1^T X^T); layer-1 output channels permuted by
// chan(lg*8+j) = (j>>2)*16 + lg*4 + (j&3) so C regs ARE the layer-2 A-fragment.
// launch_bounds(256,3): (256,4) forced VGPR=64 -> scratch spills (r10).
__global__ __launch_bounds__(256, 3)
void afno_mfma(const float* __restrict__ x,
               const float* __restrict__ w1,
               const float* __restrict__ b1,
               const float* __restrict__ w2,
               const float* __restrict__ b2,
               float* __restrict__ out) {
    __shared__ unsigned short xs[256 * XROW];  // raw bf16 x, stride-padded  18 KB
    __shared__ float twc[544];                 // cos(2*pi*m/512), idx m+(m>>4)
    __shared__ float tws[544];                 // sin
    __shared__ float jslab[4 * 544];           // per-wave f32 [16][33] jump slab

    int bid = blockIdx.x;
    int w  = bid >> 5;                    // 0..46
    int bn = bid & 31;
    int b = bn >> 3, n = bn & 7;

    int tid = threadIdx.x;
    int wv = tid >> 6;
    int lane = tid & 63;
    int lg = lane >> 4;
    int l15 = lane & 15;
    int krow = lg * 8;

    // ---- stage x rows (raw bf16, rows padded to a 32-multiple) + twiddles ----
    int rows = 0;
    #pragma unroll
    for (int q = 0; q < 4; ++q) {
        Task t2 = task_params((w << 2) | q);
        rows = rows > (t2.t_hi + 1) ? rows : (t2.t_hi + 1);
    }
    rows = (rows + 31) & ~31;
    rows = rows > 256 ? 256 : rows;
    for (int idx = tid; idx < rows * 16; idx += 256) {
        int row = idx >> 4, cp = idx & 15;
        float2 v = *(const float2*)(x + (b * 256 + row) * 256 + n * 32 + cp * 2);
        unsigned int pk = (unsigned int)f2bf(v.x) | ((unsigned int)f2bf(v.y) << 16);
        *(unsigned int*)(xs + row * XROW + cp * 2) = pk;
    }
    for (int m = tid; m < 512; m += 256) {
        float sv, cv;
        sincosf(6.28318530717958647692f * (float)m * (1.0f / 512.0f), &sv, &cv);
        twc[m + (m >> 4)] = cv;
        tws[m + (m >> 4)] = sv;
    }

    Task tk = task_params((w << 2) | wv);
    int P = 512 >> tk.sh;
    float invSqrtP = rsqrtf((float)P);

    // ---- weights -> bf16 fragments; W1 carries 1/sqrt(P); W2 rows in chan order ----
    const float* w1r = w1 + n * 1024;
    const float* w1i = w1 + (8 + n) * 1024;
    const float* w2r = w2 + n * 1024;
    const float* w2i = w2 + (8 + n) * 1024;
    short8v W10[2], W11[2], W11n[2], W20[2], W21[2], W21n[2];
    #pragma unroll
    for (int h = 0; h < 2; ++h) {
        int col = h * 16 + l15;
        #pragma unroll
        for (int j = 0; j < 8; ++j) {
            W10[h][j]  = (short)f2bf(w1r[(krow + j) * 32 + col] * invSqrtP);
            W11[h][j]  = (short)f2bf(w1i[(krow + j) * 32 + col] * invSqrtP);
            W11n[h][j] = W11[h][j] ^ (short)0x8000;
            int crow = ((j >> 2) * 16) + (lg * 4) + (j & 3);   // chan permutation
            W20[h][j]  = (short)f2bf(w2r[crow * 32 + col]);
            W21[h][j]  = (short)f2bf(w2i[crow * 32 + col]);
            W21n[h][j] = W21[h][j] ^ (short)0x8000;
        }
    }
    f32x4 b1rv[2], b1iv[2];
    float b2r_[2], b2i_[2];
    #pragma unroll
    for (int h = 0; h < 2; ++h) {
        int base = n * 32 + h * 16 + lg * 4;
        b1rv[h] = f32x4{b1[base], b1[base + 1], b1[base + 2], b1[base + 3]};
        b1iv[h] = f32x4{b1[256 + base], b1[256 + base + 1], b1[256 + base + 2], b1[256 + base + 3]};
        b2r_[h] = b2[n * 32 + h * 16 + l15];
        b2i_[h] = b2[256 + n * 32 + h * 16 + l15];
    }
    __syncthreads();   // only block barrier

    int pA5 = 0, mA5 = 0;
    int prow5[4], mrow5[4];
    float Xre[8] = {0,0,0,0,0,0,0,0}, Xim[8] = {0,0,0,0,0,0,0,0};

// Prefix jump via MFMA. jump_s may be a 16-multiple: rows >= jump_s in the
// last K-block get a zeroed twiddle A-fragment (padded xs rows are finite).
#define JUMP_X(js_) do { \
        f32x4 jre0 = {0,0,0,0}, jre1 = {0,0,0,0}, jim0 = {0,0,0,0}, jim1 = {0,0,0,0}; \
        int nkk_ = ((js_) + 31) >> 5; \
        int tail_ = (js_) & 31; \
        for (int kk = 0; kk < nkk_; ++kk) { \
            int sb_ = kk * 32; \
            short8v ac_, an2_; \
            bool zb_ = (tail_ != 0) && (kk == nkk_ - 1) && (krow >= tail_); \
            if (zb_) { \
                _Pragma("unroll") \
                for (int j = 0; j < 8; ++j) { ac_[j] = 0; an2_[j] = 0; } \
            } else { \
                int mj_ = (pA5 * (sb_ + krow)) & 511; \
                _Pragma("unroll") \
                for (int j = 0; j < 8; ++j) { \
                    int mi2_ = mj_ + (mj_ >> 4); \
                    ac_[j]  = (short)f2bf(twc[mi2_]); \
                    an2_[j] = (short)f2bf(-tws[mi2_]); \
                    mj_ = (mj_ + pA5) & 511; \
                } \
            } \
            short8v bx0_, bx1_; \
            _Pragma("unroll") \
            for (int j = 0; j < 8; ++j) { \
                int base_ = (sb_ + krow + j) * XROW + l15; \
                bx0_[j] = (short)xs[base_]; \
                bx1_[j] = (short)xs[base_ + 16]; \
            } \
            jre0 = MFMA(BF(ac_),  BF(bx0_), jre0, 0, 0, 0); \
            jim0 = MFMA(BF(an2_), BF(bx0_), jim0, 0, 0, 0); \
            jre1 = MFMA(BF(ac_),  BF(bx1_), jre1, 0, 0, 0); \
            jim1 = MFMA(BF(an2_), BF(bx1_), jim1, 0, 0, 0); \
        } \
        float* jt_ = jslab + wv * 544; \
        _Pragma("unroll") \
        for (int r = 0; r < 4; ++r) { \
            jt_[(lg * 4 + r) * 33 + l15]      = jre0[r]; \
            jt_[(lg * 4 + r) * 33 + 16 + l15] = jre1[r]; \
        } \
        LDS_FENCE(); \
        _Pragma("unroll") \
        for (int j = 0; j < 8; ++j) Xre[j] = jt_[l15 * 33 + krow + j]; \
        LDS_FENCE(); \
        _Pragma("unroll") \
        for (int r = 0; r < 4; ++r) { \
            jt_[(lg * 4 + r) * 33 + l15]      = jim0[r]; \
            jt_[(lg * 4 + r) * 33 + 16 + l15] = jim1[r]; \
        } \
        LDS_FENCE(); \
        _Pragma("unroll") \
        for (int j = 0; j < 8; ++j) Xim[j] = jt_[l15 * 33 + krow + j]; \
        LDS_FENCE(); \
    } while (0)

#define UPDATE_X(sidx) do { \
        int mi_ = mA5 + (mA5 >> 4); \
        float tc_ = twc[mi_], tsn_ = tws[mi_]; \
        mA5 = (mA5 + pA5) & 511; \
        short4v xa_ = *(const short4v*)(xs + (sidx) * XROW + krow); \
        short4v xb_ = *(const short4v*)(xs + (sidx) * XROW + krow + 4); \
        _Pragma("unroll") \
        for (int j = 0; j < 4; ++j) { \
            float xf = bf2f((unsigned short)xa_[j]); \
            Xre[j] = fmaf(xf, tc_, Xre[j]); \
            Xim[j] = fmaf(xf, -tsn_, Xim[j]); \
            float xg = bf2f((unsigned short)xb_[j]); \
            Xre[4 + j] = fmaf(xg, tc_, Xre[4 + j]); \
            Xim[4 + j] = fmaf(xg, -tsn_, Xim[4 + j]); \
        } } while (0)

#define STEP_CORE(sidx, do_upd, DEST) do { \
        if (do_upd) UPDATE_X(sidx); \
        short8v ar_, ai_; \
        _Pragma("unroll") \
        for (int j = 0; j < 8; ++j) { \
            ar_[j] = (short)f2bf(Xre[j]); \
            ai_[j] = (short)f2bf(Xim[j]); \
        } \
        f32x4 o1r_[2], o1i_[2]; \
        _Pragma("unroll") \
        for (int h = 0; h < 2; ++h) { \
            o1r_[h] = MFMA(BF(W10[h]),  BF(ar_), b1rv[h], 0, 0, 0); \
            o1r_[h] = MFMA(BF(W11n[h]), BF(ai_), o1r_[h], 0, 0, 0); \
            o1i_[h] = MFMA(BF(W10[h]),  BF(ai_), b1iv[h], 0, 0, 0); \
            o1i_[h] = MFMA(BF(W11[h]),  BF(ar_), o1i_[h], 0, 0, 0); \
        } \
        /* relu + per-lane repack: C regs ARE the layer-2 A-frag (chan perm) */ \
        short8v a2r_, a2i_; \
        _Pragma("unroll") \
        for (int j = 0; j < 8; ++j) { \
            a2r_[j] = (short)f2bf(fmaxf(o1r_[j >> 2][j & 3], 0.f)); \
            a2i_[j] = (short)f2bf(fmaxf(o1i_[j >> 2][j & 3], 0.f)); \
        } \
        f32x4 o2r_[2], o2i_[2]; \
        _Pragma("unroll") \
        for (int h = 0; h < 2; ++h) { \
            f32x4 cr = {b2r_[h], b2r_[h], b2r_[h], b2r_[h]}; \
            f32x4 ci = {b2i_[h], b2i_[h], b2i_[h], b2i_[h]}; \
            o2r_[h] = MFMA(BF(a2r_), BF(W20[h]), cr, 0, 0, 0); \
            o2r_[h] = MFMA(BF(a2i_), BF(W21n[h]), o2r_[h], 0, 0, 0); \
            o2i_[h] = MFMA(BF(a2i_), BF(W20[h]), ci, 0, 0, 0); \
            o2i_[h] = MFMA(BF(a2r_), BF(W21[h]), o2i_[h], 0, 0, 0); \
        } \
        float sh0 = 0.f, sh1 = 0.f; \
        _Pragma("unroll") \
        for (int r = 0; r < 4; ++r) { \
            int mi_ = mrow5[r] + (mrow5[r] >> 4); \
            float tc_ = twc[mi_], tsn_ = tws[mi_]; \
            mrow5[r] = (mrow5[r] + prow5[r]) & 511; \
            float v0r = o2r_[0][r]; v0r -= __builtin_amdgcn_fmed3f(v0r, -LAM, LAM); \
            float v0i = o2i_[0][r]; v0i -= __builtin_amdgcn_fmed3f(v0i, -LAM, LAM); \
            sh0 = fmaf(v0r, tc_, sh0); sh0 = fmaf(-v0i, tsn_, sh0); \
            float v1r = o2r_[1][r]; v1r -= __builtin_amdgcn_fmed3f(v1r, -LAM, LAM); \
            float v1i = o2i_[1][r]; v1i -= __builtin_amdgcn_fmed3f(v1i, -LAM, LAM); \
            sh1 = fmaf(v1r, tc_, sh1); sh1 = fmaf(-v1i, tsn_, sh1); \
        } \
        sh0 += __shfl_xor(sh0, 16); \
        sh1 += __shfl_xor(sh1, 16); \
        if (P > 8) { sh0 += __shfl_xor(sh0, 32); sh1 += __shfl_xor(sh1, 32); } \
        DEST = (lane & 16) ? sh1 : sh0; \
    } while (0)

    if (tk.jump_s == 256) {
        // ---- mega2 P=512 wave: 2 chunks, one output row (t=255), one atomic ----
        float acc = 0.f;
        for (int nc = 0; nc < 2; ++nc) {
            int cb_ = (tk.c16 + nc) * 16;
            pA5 = (cb_ + l15) & 511;
            #pragma unroll
            for (int r = 0; r < 4; ++r) {
                prow5[r] = (cb_ + lg * 4 + r) & 511;
                mrow5[r] = (prow5[r] * 255) & 511;
            }
            JUMP_X(256);
            float v_;
            STEP_CORE(255, false, v_);
            acc += v_;
        }
        if (lane < 32)
            atomicAdd(out + (b * 256 + 255) * 256 + n * 32 + (lane & 31), acc * invSqrtP);
        return;
    }

    int cbase = tk.c16 * 16;
    pA5 = ((cbase + l15) << tk.sh) & 511;
    #pragma unroll
    for (int r = 0; r < 4; ++r) {
        prow5[r] = ((cbase + lg * 4 + r) << tk.sh) & 511;
        mrow5[r] = (prow5[r] * tk.t_lo) & 511;
    }

    bool jumped = tk.jump_s > 0;
    if (jumped) {
        JUMP_X(tk.jump_s);
        mA5 = (pA5 * tk.jump_s) & 511;
    } else {
        for (int s = 0; s < tk.t_lo; ++s) UPDATE_X(s);
    }

    int s = tk.t_lo;
    bool skip0 = jumped;
    while (s + 1 <= tk.t_hi) {
        {
            float v_;
            STEP_CORE(s, !skip0, v_);
            if (lane < 32)
                atomicAdd(out + (b * 256 + s) * 256 + n * 32 + (lane & 31), v_ * invSqrtP);
        }
        {
            float v_;
            STEP_CORE(s + 1, true, v_);
            if (lane < 32)
                atomicAdd(out + (b * 256 + s + 1) * 256 + n * 32 + (lane & 31), v_ * invSqrtP);
        }
        skip0 = false;
        s += 2;
    }
    if (s <= tk.t_hi) {
        float v_;
        STEP_CORE(s, !skip0, v_);
        if (lane < 32)
            atomicAdd(out + (b * 256 + s) * 256 + n * 32 + (lane & 31), v_ * invSqrtP);
    }
}

extern "C" void kernel_launch(void* const* d_in, const int* in_sizes, int n_in,
                              void* d_out, int out_size, void* d_ws, size_t ws_size,
                              hipStream_t stream) {
    const float* x  = (const float*)d_in[0];
    const float* w1 = (const float*)d_in[1];
    const float* b1 = (const float*)d_in[2];
    const float* w2 = (const float*)d_in[3];
    const float* b2 = (const float*)d_in[4];
    float* out = (float*)d_out;

    // out = x (the "+ x" residual), then the main kernel atomically accumulates.
    hipMemcpyAsync(out, x, (size_t)(4 * 256 * 256) * sizeof(float),
                   hipMemcpyDeviceToDevice, stream);
    hipLaunchKernelGGL(afno_mfma, dim3(1504), dim3(256), 0, stream,
                       x, w1, b1, w2, b2, out);
}

// Round 19
// 56.523 us; speedup vs baseline: 1.1197x; 1.0297x over previous
//
#include <hip/hip_runtime.h>
#include <math.h>

#define LAM 0.01f

typedef __bf16 bf16x8 __attribute__((ext_vector_type(8)));
typedef float f32x4 __attribute__((ext_vector_type(4)));
typedef short short8v __attribute__((ext_vector_type(8)));
typedef short short4v __attribute__((ext_vector_type(4)));

#define BF(v) __builtin_bit_cast(bf16x8, (v))
#define MFMA __builtin_amdgcn_mfma_f32_16x16x32_bf16
#define XROW 36   // xs row stride in shorts (72B): lg-groups land 2-way (free)
#define LDS_FENCE() do { asm volatile("s_waitcnt lgkmcnt(0)" ::: "memory"); \
                         __builtin_amdgcn_sched_barrier(0); } while (0)

__device__ __forceinline__ unsigned short f2bf(float f) {
    __bf16 h = (__bf16)f;
    return __builtin_bit_cast(unsigned short, h);
}
__device__ __forceinline__ float bf2f(unsigned short u) {
    unsigned int v = ((unsigned int)u) << 16;
    return __builtin_bit_cast(float, v);
}

// 188 wave-tasks/(b,n), tau = (block_w<<2)|wv. sh = 9-log2(P); twiddles in
// 512-space. jump_s is EXCLUSIVE of t_lo (covers s < t_lo) so every steady
// step does an update -> uniform 8 pairs per 16-step segment (r19).
// Mega P=512 tasks cover 2 chunks each (16 tasks).
struct Task { int sh, c16, t_lo, t_hi, jump_s; };
__device__ __forceinline__ Task task_params(int tau) {
    Task tk;
    if (tau < 16)       { tk.sh = 0; tk.c16 = tau * 2; tk.t_lo = 255; tk.t_hi = 255; tk.jump_s = 256; }   // P=512 mega2
    else if (tau < 144) { int u = tau - 16;  int seg = u >> 4; tk.sh = 1; tk.c16 = u & 15;
                          tk.t_lo = 127 + 16 * seg; tk.t_hi = tk.t_lo + 15; tk.jump_s = tk.t_lo; }        // P=256
    else if (tau < 176) { int u = tau - 144; int seg = u >> 3; tk.sh = 2; tk.c16 = u & 7;
                          tk.t_lo = 63 + 16 * seg; tk.t_hi = tk.t_lo + 15; tk.jump_s = tk.t_lo; }         // P=128
    else if (tau < 184) { int u = tau - 176; int seg = u >> 2; tk.sh = 3; tk.c16 = u & 3;
                          tk.t_lo = 31 + 16 * seg; tk.t_hi = tk.t_lo + 15; tk.jump_s = tk.t_lo; }         // P=64
    else if (tau < 186) { tk.sh = 4; tk.c16 = tau - 184; tk.t_lo = 15; tk.t_hi = 30; tk.jump_s = 0; }     // P=32
    else if (tau == 186){ tk.sh = 5; tk.c16 = 0; tk.t_lo = 7; tk.t_hi = 14; tk.jump_s = 0; }              // P=16
    else                { tk.sh = 6; tk.c16 = 0; tk.t_lo = 0; tk.t_hi = 6;  tk.jump_s = 0; }              // P=8
    return tk;
}

// MFMA layouts (m89-verified). Layer1 transposed; layer-1 output channels
// permuted so C regs ARE the layer-2 A-fragment (r10). r19: fence-free 2-step
// register batching (STEP2) -- the serial per-step chain was ~1600cyc with
// only ~2 waves/SIMD to hide it (r16-r18 all ~58us); two independent chains
// double ILP at identical occupancy. launch_bounds(256,3): (256,4) spilled (r10).
__global__ __launch_bounds__(256, 3)
void afno_mfma(const float* __restrict__ x,
               const float* __restrict__ w1,
               const float* __restrict__ b1,
               const float* __restrict__ w2,
               const float* __restrict__ b2,
               float* __restrict__ out) {
    __shared__ unsigned short xs[256 * XROW];  // raw bf16 x, stride-padded  18 KB
    __shared__ float2 tw[544];                 // (cos,sin)(2pi m/512), idx m+(m>>4)
    __shared__ float jslab[4 * 544];           // per-wave f32 [16][33] jump slab

    int bid = blockIdx.x;
    int w  = bid >> 5;                    // 0..46
    int bn = bid & 31;
    int b = bn >> 3, n = bn & 7;

    int tid = threadIdx.x;
    int wv = tid >> 6;
    int lane = tid & 63;
    int lg = lane >> 4;
    int l15 = lane & 15;
    int krow = lg * 8;

    // ---- stage x rows (raw bf16, rows padded to a 32-multiple) + twiddles ----
    int rows = 0;
    #pragma unroll
    for (int q = 0; q < 4; ++q) {
        Task t2 = task_params((w << 2) | q);
        rows = rows > (t2.t_hi + 1) ? rows : (t2.t_hi + 1);
    }
    rows = (rows + 31) & ~31;
    rows = rows > 256 ? 256 : rows;
    for (int idx = tid; idx < rows * 16; idx += 256) {
        int row = idx >> 4, cp = idx & 15;
        float2 v = *(const float2*)(x + (b * 256 + row) * 256 + n * 32 + cp * 2);
        unsigned int pk = (unsigned int)f2bf(v.x) | ((unsigned int)f2bf(v.y) << 16);
        *(unsigned int*)(xs + row * XROW + cp * 2) = pk;
    }
    for (int m = tid; m < 512; m += 256) {
        float sv, cv;
        sincosf(6.28318530717958647692f * (float)m * (1.0f / 512.0f), &sv, &cv);
        tw[m + (m >> 4)] = make_float2(cv, sv);
    }

    Task tk = task_params((w << 2) | wv);
    int P = 512 >> tk.sh;
    float invSqrtP = rsqrtf((float)P);

    // ---- weights -> bf16 fragments; W1 carries 1/sqrt(P); W2 rows in chan order ----
    const float* w1r = w1 + n * 1024;
    const float* w1i = w1 + (8 + n) * 1024;
    const float* w2r = w2 + n * 1024;
    const float* w2i = w2 + (8 + n) * 1024;
    short8v W10[2], W11[2], W11n[2], W20[2], W21[2], W21n[2];
    #pragma unroll
    for (int h = 0; h < 2; ++h) {
        int col = h * 16 + l15;
        #pragma unroll
        for (int j = 0; j < 8; ++j) {
            W10[h][j]  = (short)f2bf(w1r[(krow + j) * 32 + col] * invSqrtP);
            W11[h][j]  = (short)f2bf(w1i[(krow + j) * 32 + col] * invSqrtP);
            W11n[h][j] = W11[h][j] ^ (short)0x8000;
            int crow = ((j >> 2) * 16) + (lg * 4) + (j & 3);   // chan permutation
            W20[h][j]  = (short)f2bf(w2r[crow * 32 + col]);
            W21[h][j]  = (short)f2bf(w2i[crow * 32 + col]);
            W21n[h][j] = W21[h][j] ^ (short)0x8000;
        }
    }
    f32x4 b1rv[2], b1iv[2];
    float b2r_[2], b2i_[2];
    #pragma unroll
    for (int h = 0; h < 2; ++h) {
        int base = n * 32 + h * 16 + lg * 4;
        b1rv[h] = f32x4{b1[base], b1[base + 1], b1[base + 2], b1[base + 3]};
        b1iv[h] = f32x4{b1[256 + base], b1[256 + base + 1], b1[256 + base + 2], b1[256 + base + 3]};
        b2r_[h] = b2[n * 32 + h * 16 + l15];
        b2i_[h] = b2[256 + n * 32 + h * 16 + l15];
    }
    __syncthreads();   // only block barrier

    int pA5 = 0, mA5 = 0;
    int prow5[4], mrow5[4];
    float Xre[8] = {0,0,0,0,0,0,0,0}, Xim[8] = {0,0,0,0,0,0,0,0};

// Prefix jump via MFMA: X = sum_{s < js_} e^{-i th} x[s]. Per-j validity mask
// (s-index sb_+krow+j < js_) handles arbitrary js_; padded xs rows are finite.
#define JUMP_X(js_) do { \
        f32x4 jre0 = {0,0,0,0}, jre1 = {0,0,0,0}, jim0 = {0,0,0,0}, jim1 = {0,0,0,0}; \
        int nkk_ = ((js_) + 31) >> 5; \
        for (int kk = 0; kk < nkk_; ++kk) { \
            int sb_ = kk * 32; \
            short8v ac_, an2_; \
            int mj_ = (pA5 * (sb_ + krow)) & 511; \
            _Pragma("unroll") \
            for (int j = 0; j < 8; ++j) { \
                int mi2_ = mj_ + (mj_ >> 4); \
                float2 t_ = tw[mi2_]; \
                bool ok_ = (sb_ + krow + j) < (js_); \
                ac_[j]  = ok_ ? (short)f2bf(t_.x)  : (short)0; \
                an2_[j] = ok_ ? (short)f2bf(-t_.y) : (short)0; \
                mj_ = (mj_ + pA5) & 511; \
            } \
            short8v bx0_, bx1_; \
            _Pragma("unroll") \
            for (int j = 0; j < 8; ++j) { \
                int base_ = (sb_ + krow + j) * XROW + l15; \
                bx0_[j] = (short)xs[base_]; \
                bx1_[j] = (short)xs[base_ + 16]; \
            } \
            jre0 = MFMA(BF(ac_),  BF(bx0_), jre0, 0, 0, 0); \
            jim0 = MFMA(BF(an2_), BF(bx0_), jim0, 0, 0, 0); \
            jre1 = MFMA(BF(ac_),  BF(bx1_), jre1, 0, 0, 0); \
            jim1 = MFMA(BF(an2_), BF(bx1_), jim1, 0, 0, 0); \
        } \
        float* jt_ = jslab + wv * 544; \
        _Pragma("unroll") \
        for (int r = 0; r < 4; ++r) { \
            jt_[(lg * 4 + r) * 33 + l15]      = jre0[r]; \
            jt_[(lg * 4 + r) * 33 + 16 + l15] = jre1[r]; \
        } \
        LDS_FENCE(); \
        _Pragma("unroll") \
        for (int j = 0; j < 8; ++j) Xre[j] = jt_[l15 * 33 + krow + j]; \
        LDS_FENCE(); \
        _Pragma("unroll") \
        for (int r = 0; r < 4; ++r) { \
            jt_[(lg * 4 + r) * 33 + l15]      = jim0[r]; \
            jt_[(lg * 4 + r) * 33 + 16 + l15] = jim1[r]; \
        } \
        LDS_FENCE(); \
        _Pragma("unroll") \
        for (int j = 0; j < 8; ++j) Xim[j] = jt_[l15 * 33 + krow + j]; \
        LDS_FENCE(); \
    } while (0)

#define UPDATE_X(sidx) do { \
        int mi_ = mA5 + (mA5 >> 4); \
        float2 t_ = tw[mi_]; \
        mA5 = (mA5 + pA5) & 511; \
        short4v xa_ = *(const short4v*)(xs + (sidx) * XROW + krow); \
        short4v xb_ = *(const short4v*)(xs + (sidx) * XROW + krow + 4); \
        _Pragma("unroll") \
        for (int j = 0; j < 4; ++j) { \
            float xf = bf2f((unsigned short)xa_[j]); \
            Xre[j] = fmaf(xf, t_.x, Xre[j]); \
            Xim[j] = fmaf(xf, -t_.y, Xim[j]); \
            float xg = bf2f((unsigned short)xb_[j]); \
            Xre[4 + j] = fmaf(xg, t_.x, Xre[4 + j]); \
            Xim[4 + j] = fmaf(xg, -t_.y, Xim[4 + j]); \
        } } while (0)

#define SNAP_A(arv, aiv) do { \
        _Pragma("unroll") \
        for (int j = 0; j < 8; ++j) { \
            (arv)[j] = (short)f2bf(Xre[j]); \
            (aiv)[j] = (short)f2bf(Xim[j]); \
        } } while (0)

#define L1(arv, aiv, o1r_, o1i_) do { \
        _Pragma("unroll") \
        for (int h = 0; h < 2; ++h) { \
            o1r_[h] = MFMA(BF(arv), BF(W10[h]),  b1rv[h], 0, 0, 0); \
            o1r_[h] = MFMA(BF(aiv), BF(W11n[h]), o1r_[h], 0, 0, 0); \
            o1i_[h] = MFMA(BF(aiv), BF(W10[h]),  b1iv[h], 0, 0, 0); \
            o1i_[h] = MFMA(BF(arv), BF(W11[h]),  o1i_[h], 0, 0, 0); \
        } } while (0)

#define REPACK(o1r_, o1i_, a2r_, a2i_) do { \
        _Pragma("unroll") \
        for (int j = 0; j < 8; ++j) { \
            (a2r_)[j] = (short)f2bf(fmaxf(o1r_[j >> 2][j & 3], 0.f)); \
            (a2i_)[j] = (short)f2bf(fmaxf(o1i_[j >> 2][j & 3], 0.f)); \
        } } while (0)

#define L2(a2r_, a2i_, o2r_, o2i_) do { \
        _Pragma("unroll") \
        for (int h = 0; h < 2; ++h) { \
            f32x4 cr = {b2r_[h], b2r_[h], b2r_[h], b2r_[h]}; \
            f32x4 ci = {b2i_[h], b2i_[h], b2i_[h], b2i_[h]}; \
            o2r_[h] = MFMA(BF(a2r_), BF(W20[h]),  cr, 0, 0, 0); \
            o2r_[h] = MFMA(BF(a2i_), BF(W21n[h]), o2r_[h], 0, 0, 0); \
            o2i_[h] = MFMA(BF(a2i_), BF(W20[h]),  ci, 0, 0, 0); \
            o2i_[h] = MFMA(BF(a2r_), BF(W21[h]),  o2i_[h], 0, 0, 0); \
        } } while (0)

// epilogue with explicit per-row twiddles tR[4]; no mrow walk inside
#define EPI(o2r_, o2i_, tR, DEST) do { \
        float sh0 = 0.f, sh1 = 0.f; \
        _Pragma("unroll") \
        for (int r = 0; r < 4; ++r) { \
            float v0r = o2r_[0][r]; v0r -= __builtin_amdgcn_fmed3f(v0r, -LAM, LAM); \
            float v0i = o2i_[0][r]; v0i -= __builtin_amdgcn_fmed3f(v0i, -LAM, LAM); \
            sh0 = fmaf(v0r, (tR)[r].x, sh0); sh0 = fmaf(-v0i, (tR)[r].y, sh0); \
            float v1r = o2r_[1][r]; v1r -= __builtin_amdgcn_fmed3f(v1r, -LAM, LAM); \
            float v1i = o2i_[1][r]; v1i -= __builtin_amdgcn_fmed3f(v1i, -LAM, LAM); \
            sh1 = fmaf(v1r, (tR)[r].x, sh1); sh1 = fmaf(-v1i, (tR)[r].y, sh1); \
        } \
        sh0 += __shfl_xor(sh0, 16); \
        sh1 += __shfl_xor(sh1, 16); \
        if (P > 8) { sh0 += __shfl_xor(sh0, 32); sh1 += __shfl_xor(sh1, 32); } \
        DEST = (lane & 16) ? sh1 : sh0; \
    } while (0)

#define STEP1(sidx, do_upd) do { \
        if (do_upd) UPDATE_X(sidx); \
        short8v ar_, ai_, a2r_, a2i_; \
        SNAP_A(ar_, ai_); \
        f32x4 o1r_[2], o1i_[2], o2r_[2], o2i_[2]; \
        L1(ar_, ai_, o1r_, o1i_); \
        REPACK(o1r_, o1i_, a2r_, a2i_); \
        L2(a2r_, a2i_, o2r_, o2i_); \
        float2 tR[4]; \
        _Pragma("unroll") \
        for (int r = 0; r < 4; ++r) { \
            int mi_ = mrow5[r] + (mrow5[r] >> 4); \
            tR[r] = tw[mi_]; \
            mrow5[r] = (mrow5[r] + prow5[r]) & 511; \
        } \
        float v_; \
        EPI(o2r_, o2i_, tR, v_); \
        if (lane < 32) \
            atomicAdd(out + (b * 256 + (sidx)) * 256 + n * 32 + (lane & 31), v_ * invSqrtP); \
    } while (0)

// two independent chains, fence-free; atomics at the end
#define STEP2(s0) do { \
        short8v ar0_, ai0_, ar1_, ai1_, a2r0_, a2i0_, a2r1_, a2i1_; \
        UPDATE_X(s0);     SNAP_A(ar0_, ai0_); \
        UPDATE_X((s0)+1); SNAP_A(ar1_, ai1_); \
        f32x4 o1r0_[2], o1i0_[2], o1r1_[2], o1i1_[2]; \
        L1(ar0_, ai0_, o1r0_, o1i0_); \
        L1(ar1_, ai1_, o1r1_, o1i1_); \
        REPACK(o1r0_, o1i0_, a2r0_, a2i0_); \
        REPACK(o1r1_, o1i1_, a2r1_, a2i1_); \
        f32x4 o2r0_[2], o2i0_[2], o2r1_[2], o2i1_[2]; \
        L2(a2r0_, a2i0_, o2r0_, o2i0_); \
        L2(a2r1_, a2i1_, o2r1_, o2i1_); \
        float2 tR0[4], tR1[4]; \
        _Pragma("unroll") \
        for (int r = 0; r < 4; ++r) { \
            int m0_ = mrow5[r]; \
            int m1_ = (m0_ + prow5[r]) & 511; \
            tR0[r] = tw[m0_ + (m0_ >> 4)]; \
            tR1[r] = tw[m1_ + (m1_ >> 4)]; \
            mrow5[r] = (m1_ + prow5[r]) & 511; \
        } \
        float v0_, v1_; \
        EPI(o2r0_, o2i0_, tR0, v0_); \
        EPI(o2r1_, o2i1_, tR1, v1_); \
        if (lane < 32) { \
            float* o_ = out + (b * 256 + (s0)) * 256 + n * 32 + (lane & 31); \
            atomicAdd(o_, v0_ * invSqrtP); \
            atomicAdd(o_ + 256, v1_ * invSqrtP); \
        } \
    } while (0)

    if (tk.jump_s == 256) {
        // ---- mega2 P=512 wave: 2 chunks, one output row (t=255), one atomic ----
        float acc = 0.f;
        for (int nc = 0; nc < 2; ++nc) {
            int cb_ = (tk.c16 + nc) * 16;
            pA5 = (cb_ + l15) & 511;
            #pragma unroll
            for (int r = 0; r < 4; ++r) {
                prow5[r] = (cb_ + lg * 4 + r) & 511;
                mrow5[r] = (prow5[r] * 255) & 511;
            }
            JUMP_X(256);
            float v_;
            {
                short8v ar_, ai_, a2r_, a2i_;
                SNAP_A(ar_, ai_);
                f32x4 o1r_[2], o1i_[2], o2r_[2], o2i_[2];
                L1(ar_, ai_, o1r_, o1i_);
                REPACK(o1r_, o1i_, a2r_, a2i_);
                L2(a2r_, a2i_, o2r_, o2i_);
                float2 tR[4];
                #pragma unroll
                for (int r = 0; r < 4; ++r) {
                    int mi_ = mrow5[r] + (mrow5[r] >> 4);
                    tR[r] = tw[mi_];
                }
                EPI(o2r_, o2i_, tR, v_);
            }
            acc += v_;
        }
        if (lane < 32)
            atomicAdd(out + (b * 256 + 255) * 256 + n * 32 + (lane & 31), acc * invSqrtP);
        return;
    }

    int cbase = tk.c16 * 16;
    pA5 = ((cbase + l15) << tk.sh) & 511;
    #pragma unroll
    for (int r = 0; r < 4; ++r) {
        prow5[r] = ((cbase + lg * 4 + r) << tk.sh) & 511;
        mrow5[r] = (prow5[r] * tk.t_lo) & 511;
    }

    if (tk.jump_s > 0) {
        JUMP_X(tk.jump_s);                    // covers s < t_lo
        mA5 = (pA5 * tk.jump_s) & 511;        // first update at s = t_lo
    } else {
        for (int s = 0; s < tk.t_lo; ++s) UPDATE_X(s);
    }

    int s = tk.t_lo;
    while (s + 1 <= tk.t_hi) {
        STEP2(s);
        s += 2;
    }
    if (s <= tk.t_hi) {
        STEP1(s, true);
    }
}

extern "C" void kernel_launch(void* const* d_in, const int* in_sizes, int n_in,
                              void* d_out, int out_size, void* d_ws, size_t ws_size,
                              hipStream_t stream) {
    const float* x  = (const float*)d_in[0];
    const float* w1 = (const float*)d_in[1];
    const float* b1 = (const float*)d_in[2];
    const float* w2 = (const float*)d_in[3];
    const float* b2 = (const float*)d_in[4];
    float* out = (float*)d_out;

    // out = x (the "+ x" residual), then the main kernel atomically accumulates.
    hipMemcpyAsync(out, x, (size_t)(4 * 256 * 256) * sizeof(float),
                   hipMemcpyDeviceToDevice, stream);
    hipLaunchKernelGGL(afno_mfma, dim3(1504), dim3(256), 0, stream,
                       x, w1, b1, w2, b2, out);
}